// Round 6
// baseline (292.950 us; speedup 1.0000x reference)
//
#include <hip/hip_runtime.h>
#include <hip/hip_bf16.h>
#include <hip/hip_fp16.h>
#include <math.h>

#define NEG_SLOPE 0.2f

typedef __attribute__((ext_vector_type(8))) short short8v;
typedef __attribute__((ext_vector_type(4))) float f32x4;

__device__ __forceinline__ float uas(unsigned int u) { return __uint_as_float(u); }

__device__ __forceinline__ unsigned short f2bf(float x) {
    __hip_bfloat16 b = __float2bfloat16(x);
    return *(unsigned short*)&b;
}

#define NPB_SHIFT 8
#define BIN_EDGES 2048            // edges per histogram/scatter slice
#define GEMM_EPT  8               // 2048 / 256 threads (gemm fused hist)
#define BS_EPT    4               // 2048 / 512 threads (binscatter)

// ---------------- W prep: extended bf16 fragment image -----------------------
// Extended B matrix W'[144,256]: rows 0..127 = W; rows 128..135 = head-masked
// attn projections vl[4],vr[4]; rows 136..143 = 0.  Also zeroes bcount.
__global__ void k_prep(const float* __restrict__ W, const float* __restrict__ al,
                       const float* __restrict__ ar, short* __restrict__ wfrag,
                       int* __restrict__ bcount, int NB) {
    int p = blockIdx.x * 256 + threadIdx.x;   // n*32+kg, 0..4607
    if (p < NB) bcount[p] = 0;
    if (p >= 144 * 32) return;
    int n = p >> 5, kg = p & 31;
    float v[8];
    if (n < 128) {
        const float* wp = W + (size_t)n * 256 + kg * 8;
        float4 v0 = *(const float4*)wp;
        float4 v1 = *(const float4*)(wp + 4);
        v[0] = v0.x; v[1] = v0.y; v[2] = v0.z; v[3] = v0.w;
        v[4] = v1.x; v[5] = v1.y; v[6] = v1.z; v[7] = v1.w;
    } else if (n < 136) {
        int i = n - 128, hh = i & 3, lr = i >> 2;
        const float* av = lr ? ar : al;
#pragma unroll
        for (int j = 0; j < 8; j++) v[j] = 0.f;
        for (int c = 0; c < 32; c++) {
            float a = av[hh * 32 + c];
            const float* wp = W + (size_t)(hh * 32 + c) * 256 + kg * 8;
#pragma unroll
            for (int j = 0; j < 8; j++) v[j] += a * wp[j];
        }
    } else {
#pragma unroll
        for (int j = 0; j < 8; j++) v[j] = 0.f;
    }
    short s8[8];
#pragma unroll
    for (int j = 0; j < 8; j++) s8[j] = (short)f2bf(v[j]);
    int kstep = kg >> 2, ntile = n >> 4;
    int L     = (kg & 3) * 16 + (n & 15);
    int slot  = kstep * 9 + ntile;
    *(short8v*)&wfrag[(slot * 64 + L) * 8] = *(short8v*)s8;
}

// ---------------- MFMA GEMM + fused el/er + fused bucket histogram -----------
// v2: NO LDS staging of W'.  W' (72 KB) is read-only and L2-resident; each
// wave reads its B fragments as coalesced 1-KB chunks straight from global.
// LDS drops 66 KB -> 2 KB, occupancy goes VGPR-bound (launch_bounds(256,4)
// caps at 128 VGPR -> 16 waves/CU vs 5.6 before) and the staging barrier
// disappears; memory latency is hidden by TLP instead of a prefetch batch.
__global__ __launch_bounds__(256, 4) void k_gemm(const float* __restrict__ feat,
                                                 const short* __restrict__ wfrag,
                                                 unsigned short* __restrict__ hb,
                                                 float* __restrict__ el,
                                                 float* __restrict__ er, int N,
                                                 const int* __restrict__ dst,
                                                 int* __restrict__ bcount,
                                                 int E, int NB) {
    __shared__ int bh[512];         // bucket histogram (only LDS left)
    const int t    = threadIdx.x;
    const int lane = t & 63;
    const int wave = t >> 6;
    const int n0   = blockIdx.x * 64;
    const int g    = lane >> 4;     // k-quad
    const int c    = lane & 15;
    const bool do_hist = (blockIdx.x * BIN_EDGES) < E;

    if (do_hist) {
        for (int i = t; i < 512; i += 256) bh[i] = 0;
    }

    const int row = n0 + wave * 16 + c;
    const int rc  = row < N ? row : N - 1;
    const float* ap = feat + (size_t)rc * 256 + g * 8;

    f32x4 acc[9];
#pragma unroll
    for (int nt = 0; nt < 9; nt++) acc[nt] = (f32x4){0.f, 0.f, 0.f, 0.f};

#pragma unroll
    for (int ks = 0; ks < 8; ks++) {
        float4 v0 = *(const float4*)(ap + ks * 32);
        float4 v1 = *(const float4*)(ap + ks * 32 + 4);
        short s8[8];
        s8[0] = (short)f2bf(v0.x); s8[1] = (short)f2bf(v0.y);
        s8[2] = (short)f2bf(v0.z); s8[3] = (short)f2bf(v0.w);
        s8[4] = (short)f2bf(v1.x); s8[5] = (short)f2bf(v1.y);
        s8[6] = (short)f2bf(v1.z); s8[7] = (short)f2bf(v1.w);
        short8v afrag = *(short8v*)s8;
        const short* wf = wfrag + (((size_t)ks * 9) * 64 + lane) * 8;
#pragma unroll
        for (int nt = 0; nt < 9; nt++) {
            short8v b = *(const short8v*)(wf + (size_t)nt * 64 * 8);
            acc[nt] = __builtin_amdgcn_mfma_f32_16x16x32_bf16(afrag, b, acc[nt], 0, 0, 0);
        }
    }

    // ---- epilogue: C/D layout col = nt*16 + c, row = wave*16 + g*4 + r
#pragma unroll
    for (int r = 0; r < 4; r++) {
        int m = n0 + wave * 16 + g * 4 + r;
        if (m < N) {
#pragma unroll
            for (int nt = 0; nt < 8; nt++)
                hb[(size_t)m * 128 + nt * 16 + c] = f2bf(acc[nt][r]);
            float av = acc[8][r];
            if (c < 4)      el[(size_t)m * 4 + c]       = av;
            else if (c < 8) er[(size_t)m * 4 + (c - 4)] = av;
        }
    }

    // ---- fused bucket histogram (slice of 2048 edges)
    if (do_hist) {
        __syncthreads();   // bh init visible (block-uniform branch)
        int base = blockIdx.x * BIN_EDGES + t;
#pragma unroll
        for (int k = 0; k < GEMM_EPT; k++) {
            int idx = base + k * 256;
            if (idx < E) atomicAdd(&bh[dst[idx] >> NPB_SHIFT], 1);
        }
        __syncthreads();
        for (int i = t; i < NB; i += 256) {
            int h = bh[i];
            if (h) atomicAdd(&bcount[i], h);
        }
    }
}

// single-WG scan of bucket counts -> bucket bases + cursors; also start[N]=E
__global__ __launch_bounds__(512) void k_bscan(const int* __restrict__ bcount,
                                               int* __restrict__ bbase,
                                               int* __restrict__ bcur,
                                               int* __restrict__ startA,
                                               int NB, int N) {
    __shared__ int s[512];
    int t = threadIdx.x;
    int h = (t < NB) ? bcount[t] : 0;
    s[t] = h;
    __syncthreads();
    for (int off = 1; off < 512; off <<= 1) {
        int v = (t >= off) ? s[t - off] : 0;
        __syncthreads();
        s[t] += v;
        __syncthreads();
    }
    int excl = s[t] - h;
    if (t <= NB) bbase[t] = excl;     // bbase[NB] = E
    if (t < NB)  bcur[t]  = excl;
    if (t == 0)  startA[N] = s[511];  // total = E
}

// scatter edges into bucket-contiguous order, packed src|ldst<<24 (4 B/edge).
// 512 threads / 2048 edges per WG -> 489 WGs; LDS-reorder so global writes
// are coalesced runs.
__global__ __launch_bounds__(512) void k_binscatter(const int* __restrict__ src,
                                                    const int* __restrict__ dst,
                                                    int* __restrict__ bcur,
                                                    unsigned int* __restrict__ binned,
                                                    int E, int NB) {
    __shared__ int hist[512];
    __shared__ int scn[512];
    __shared__ int lcur[512];
    __shared__ int gdelta[512];
    __shared__ int ebuf[BIN_EDGES];   // 8 KB: src per local slot
    __shared__ int dbuf[BIN_EDGES];   // 8 KB: dst per local slot
    int t = threadIdx.x;
    hist[t] = 0;
    __syncthreads();
    int wbase = blockIdx.x * BIN_EDGES;
    int base  = wbase + t;
    int ne    = E - wbase; if (ne > BIN_EDGES) ne = BIN_EDGES;
    int sv[BS_EPT], dv[BS_EPT];
#pragma unroll
    for (int k = 0; k < BS_EPT; k++) {
        int idx = base + k * 512;
        if (idx < E) {
            sv[k] = src[idx];
            dv[k] = dst[idx];
            atomicAdd(&hist[dv[k] >> NPB_SHIFT], 1);
        } else {
            dv[k] = -1;
        }
    }
    __syncthreads();
    // inclusive scan of 512 counts with 512 threads (Hillis-Steele)
    scn[t] = hist[t];
    __syncthreads();
    for (int off = 1; off < 512; off <<= 1) {
        int v = (t >= off) ? scn[t - off] : 0;
        __syncthreads();
        scn[t] += v;
        __syncthreads();
    }
    // claim global ranges; set local cursors
    if (t < NB) {
        int h  = hist[t];
        int lb = scn[t] - h;
        int g  = h ? atomicAdd(&bcur[t], h) : 0;
        gdelta[t] = g - lb;
        lcur[t]   = lb;
    }
    __syncthreads();
    // local scatter into bucket-sorted LDS order
#pragma unroll
    for (int k = 0; k < BS_EPT; k++) {
        if (dv[k] >= 0) {
            int bkt  = dv[k] >> NPB_SHIFT;
            int slot = atomicAdd(&lcur[bkt], 1);
            ebuf[slot] = sv[k];
            dbuf[slot] = dv[k];
        }
    }
    __syncthreads();
    // linear write-out: address = slot + gdelta[bucket]  (coalesced runs)
    for (int j = t; j < ne; j += 512) {
        int d = dbuf[j];
        binned[j + gdelta[d >> NPB_SHIFT]] =
            (unsigned int)ebuf[j] | ((unsigned int)(d & 255) << 24);
    }
}

// one WG per bucket: degree hist -> start, then LDS-stage the node-sorted
// edges and write the bucket's CSR segment with one linear coalesced pass.
__global__ __launch_bounds__(512) void k_csr(const unsigned int* __restrict__ binned,
                                             const int* __restrict__ bbase,
                                             int* __restrict__ startA,
                                             int* __restrict__ src_csr, int N) {
    __shared__ int hist[256];
    __shared__ int scn[256];
    __shared__ int cur[256];
    __shared__ int sbuf[4096];   // 16 KB staging (max bucket ~2.8K edges expected)
    int b = blockIdx.x;
    int t = threadIdx.x;
    int base = bbase[b];
    int cnt  = bbase[b + 1] - base;
    int node0 = b << NPB_SHIFT;
    if (t < 256) hist[t] = 0;
    __syncthreads();
    for (int i = t; i < cnt; i += 512) {
        unsigned int e = binned[base + i];
        atomicAdd(&hist[e >> 24], 1);
    }
    __syncthreads();
    int h = (t < 256) ? hist[t] : 0;
    if (t < 256) scn[t] = h;
    __syncthreads();
    for (int off = 1; off < 256; off <<= 1) {
        int v = (t < 256 && t >= off) ? scn[t - off] : 0;
        __syncthreads();
        if (t < 256) scn[t] += v;
        __syncthreads();
    }
    if (t < 256) {
        int excl  = scn[t] - h;
        int gnode = node0 + t;
        if (gnode < N) startA[gnode] = base + excl;
        cur[t] = excl;
    }
    __syncthreads();
    if (cnt <= 4096) {
        for (int i = t; i < cnt; i += 512) {
            unsigned int e = binned[base + i];
            int p = atomicAdd(&cur[e >> 24], 1);
            sbuf[p] = (int)(e & 0xFFFFFFu);
        }
        __syncthreads();
        for (int i = t; i < cnt; i += 512)
            src_csr[base + i] = sbuf[i];
    } else {
        // fallback: direct scatter (degenerate distributions only)
        for (int i = t; i < cnt; i += 512) {
            unsigned int e = binned[base + i];
            int p = atomicAdd(&cur[e >> 24], 1);
            src_csr[base + p] = (int)(e & 0xFFFFFFu);
        }
    }
}

// ---------------- gather-side aggregation: one wave per dst node -------------
// unroll-8 with batched index/gather issue (8 outstanding 256-B gathers per
// wave) to hide LLC-hit latency; degree from start[w+1]-start[w].
__global__ __launch_bounds__(256) void k_agg(
        const unsigned int* __restrict__ hbu,
        const float* __restrict__ el, const float* __restrict__ er,
        const int* __restrict__ src_csr, const int* __restrict__ start,
        const float* __restrict__ bias, float* __restrict__ out, int N) {
    int wid  = blockIdx.x * 4 + (threadIdx.x >> 6);
    int lane = threadIdx.x & 63;
    if (wid >= N) return;
    int beg = __builtin_amdgcn_readfirstlane(start[wid]);
    int end = __builtin_amdgcn_readfirstlane(start[wid + 1]);
    int dg  = end - beg;
    int head = lane >> 4;   // elements (2*lane, 2*lane+1) share one head

    float er_own = er[(size_t)wid * 4 + head];   // wave-uniform per 16-lane group
    unsigned int uh = hbu[(size_t)wid * 64 + lane];  // own row, issued early
    float2 bv = ((const float2*)bias)[lane];

    float S1x = 0.f, S1y = 0.f, S2x = 0.f, S2y = 0.f, dd = 0.f;
    int i = 0;
    for (; i + 8 <= dg; i += 8) {
        int b = beg + i;
        int s[8];
#pragma unroll
        for (int k = 0; k < 8; k++) s[k] = src_csr[b + k];
        unsigned int u[8];
#pragma unroll
        for (int k = 0; k < 8; k++) u[k] = hbu[(size_t)s[k] * 64 + lane];
        float ev[8];
#pragma unroll
        for (int k = 0; k < 8; k++) ev[k] = el[(size_t)s[k] * 4 + head];
#pragma unroll
        for (int k = 0; k < 8; k++) {
            float tt = ev[k] + er_own;
            tt = fmaxf(tt, NEG_SLOPE * tt);
            float w = __expf(tt);
            float x = uas(u[k] << 16), y = uas(u[k] & 0xFFFF0000u);
            S1x += x; S1y += y;
            S2x += w * x; S2y += w * y;
            dd  += w;
        }
    }
    for (; i + 4 <= dg; i += 4) {
        int b = beg + i;
        int s[4];
#pragma unroll
        for (int k = 0; k < 4; k++) s[k] = src_csr[b + k];
        unsigned int u[4];
#pragma unroll
        for (int k = 0; k < 4; k++) u[k] = hbu[(size_t)s[k] * 64 + lane];
        float ev[4];
#pragma unroll
        for (int k = 0; k < 4; k++) ev[k] = el[(size_t)s[k] * 4 + head];
#pragma unroll
        for (int k = 0; k < 4; k++) {
            float tt = ev[k] + er_own;
            tt = fmaxf(tt, NEG_SLOPE * tt);
            float w = __expf(tt);
            float x = uas(u[k] << 16), y = uas(u[k] & 0xFFFF0000u);
            S1x += x; S1y += y;
            S2x += w * x; S2y += w * y;
            dd  += w;
        }
    }
    for (; i < dg; i++) {
        int s0 = src_csr[beg + i];
        unsigned int u0 = hbu[(size_t)s0 * 64 + lane];
        float tt = el[(size_t)s0 * 4 + head] + er_own;
        tt = fmaxf(tt, NEG_SLOPE * tt);
        float w0 = __expf(tt);
        float x0 = uas(u0 << 16), y0 = uas(u0 & 0xFFFF0000u);
        S1x += x0; S1y += y0;
        S2x += w0 * x0; S2y += w0 * y0;
        dd  += w0;
    }

    float hvx = uas(uh << 16), hvy = uas(uh & 0xFFFF0000u);
    float inv = dd > 0.f ? 1.f / dd : 0.f;
    float ox = bv.x + hvx * S1x + S2x * inv;
    float oy = bv.y + hvy * S1y + S2y * inv;
    float2 o = {ox, oy};
    ((float2*)(out + (size_t)wid * 128))[lane] = o;
}

extern "C" void kernel_launch(void* const* d_in, const int* in_sizes, int n_in,
                              void* d_out, int out_size, void* d_ws, size_t ws_size,
                              hipStream_t stream) {
    const float* feat = (const float*)d_in[0];
    const float* W_fc = (const float*)d_in[1];
    const float* al   = (const float*)d_in[2];
    const float* ar   = (const float*)d_in[3];
    const float* bias = (const float*)d_in[4];
    const int*   src  = (const int*)d_in[5];
    const int*   dst  = (const int*)d_in[6];
    const int N = in_sizes[0] / 256;
    const int E = in_sizes[5];
    const int NB = (N + 255) >> NPB_SHIFT;   // <= 512 for N <= 131072

    char* ws = (char*)d_ws;
    size_t off = 0;
    unsigned int* hbu = (unsigned int*)(ws + off); off += (size_t)N * 64 * 4; // 25.6 MB
    float* el         = (float*)(ws + off); off += (size_t)N * 4 * 4;         // 1.6 MB
    float* er         = (float*)(ws + off); off += (size_t)N * 4 * 4;         // 1.6 MB
    int* startA       = (int*)(ws + off);   off += (size_t)(N + 1) * 4;
    int* src_csr      = (int*)(ws + off);   off += (size_t)E * 4;             // 4 MB
    unsigned int* binned = (unsigned int*)(ws + off); off += (size_t)E * 4;   // 4 MB
    short* wfrag      = (short*)(ws + off); off += (size_t)72 * 64 * 8 * 2;   // 72 KB
    int* bcount       = (int*)(ws + off);   off += 2048;
    int* bbase        = (int*)(ws + off);   off += 2064;                      // NB+1
    int* bcur         = (int*)(ws + off);   off += 2048;

    float* out = (float*)d_out;

    int nblk  = (N + 63) / 64;
    int binWG = (E + BIN_EDGES - 1) / BIN_EDGES;
    int gemmWG = nblk > binWG ? nblk : binWG;   // ensure hist slices cover E

    k_prep<<<18, 256, 0, stream>>>(W_fc, al, ar, wfrag, bcount, NB);
    k_gemm<<<gemmWG, 256, 0, stream>>>(feat, wfrag, (unsigned short*)hbu,
                                       el, er, N, dst, bcount, E, NB);
    k_bscan<<<1, 512, 0, stream>>>(bcount, bbase, bcur, startA, NB, N);
    k_binscatter<<<binWG, 512, 0, stream>>>(src, dst, bcur, binned, E, NB);
    k_csr<<<NB, 512, 0, stream>>>(binned, bbase, startA, src_csr, N);
    k_agg<<<(N + 3) / 4, 256, 0, stream>>>(hbu, el, er, src_csr, startA,
                                           bias, out, N);
}

// Round 7
// 280.918 us; speedup vs baseline: 1.0428x; 1.0428x over previous
//
#include <hip/hip_runtime.h>
#include <hip/hip_bf16.h>
#include <hip/hip_fp16.h>
#include <math.h>

#define NEG_SLOPE 0.2f

typedef __attribute__((ext_vector_type(8))) short short8v;
typedef __attribute__((ext_vector_type(4))) float f32x4;

__device__ __forceinline__ float uas(unsigned int u) { return __uint_as_float(u); }

__device__ __forceinline__ unsigned short f2bf(float x) {
    __hip_bfloat16 b = __float2bfloat16(x);
    return *(unsigned short*)&b;
}

#define NPB_SHIFT 8
#define BIN_EDGES 2048            // edges per histogram/scatter slice
#define GEMM_EPT  8               // 2048 / 256 threads (gemm fused hist)
#define BS_EPT    4               // 2048 / 512 threads (binscatter)
#define GEMM_BLOCKS 512           // persistent blocks (2 per CU)

// ---------------- W prep: extended bf16 fragment image -----------------------
// Extended B matrix W'[144,256]: rows 0..127 = W; rows 128..135 = head-masked
// attn projections vl[4],vr[4]; rows 136..143 = 0.  Also zeroes bcount.
__global__ void k_prep(const float* __restrict__ W, const float* __restrict__ al,
                       const float* __restrict__ ar, short* __restrict__ wfrag,
                       int* __restrict__ bcount, int NB) {
    int p = blockIdx.x * 256 + threadIdx.x;   // n*32+kg, 0..4607
    if (p < NB) bcount[p] = 0;
    if (p >= 144 * 32) return;
    int n = p >> 5, kg = p & 31;
    float v[8];
    if (n < 128) {
        const float* wp = W + (size_t)n * 256 + kg * 8;
        float4 v0 = *(const float4*)wp;
        float4 v1 = *(const float4*)(wp + 4);
        v[0] = v0.x; v[1] = v0.y; v[2] = v0.z; v[3] = v0.w;
        v[4] = v1.x; v[5] = v1.y; v[6] = v1.z; v[7] = v1.w;
    } else if (n < 136) {
        int i = n - 128, hh = i & 3, lr = i >> 2;
        const float* av = lr ? ar : al;
#pragma unroll
        for (int j = 0; j < 8; j++) v[j] = 0.f;
        for (int c = 0; c < 32; c++) {
            float a = av[hh * 32 + c];
            const float* wp = W + (size_t)(hh * 32 + c) * 256 + kg * 8;
#pragma unroll
            for (int j = 0; j < 8; j++) v[j] += a * wp[j];
        }
    } else {
#pragma unroll
        for (int j = 0; j < 8; j++) v[j] = 0.f;
    }
    short s8[8];
#pragma unroll
    for (int j = 0; j < 8; j++) s8[j] = (short)f2bf(v[j]);
    int kstep = kg >> 2, ntile = n >> 4;
    int L     = (kg & 3) * 16 + (n & 15);
    int slot  = kstep * 9 + ntile;
    *(short8v*)&wfrag[(slot * 64 + L) * 8] = *(short8v*)s8;
}

// ---------------- MFMA GEMM + fused el/er + fused bucket histogram -----------
// v3: persistent blocks.  512 blocks (2/CU) stage ALL 72 B-slots (72 KB,
// incl. the attn ntile) into LDS ONCE, pass one barrier, then grid-stride
// over 64-row tiles with a barrier-free inner loop {A-load, 72 MFMA, store}.
// Staging is paid 512x instead of 1563x and no per-tile barrier drain; the
// per-tile A-load latency hides under the 8 co-resident waves' compute.
__global__ __launch_bounds__(256) void k_gemm(const float* __restrict__ feat,
                                              const short* __restrict__ wfrag,
                                              unsigned short* __restrict__ hb,
                                              float* __restrict__ el,
                                              float* __restrict__ er, int N,
                                              int ntiles,
                                              const int* __restrict__ dst,
                                              int* __restrict__ bcount,
                                              int E, int NB) {
    __shared__ short wlds[36864];   // 72 KB: all 72 slots, linear
    __shared__ int bh[512];         // bucket histogram
    const int t    = threadIdx.x;
    const int lane = t & 63;
    const int wave = t >> 6;
    const int g    = lane >> 4;     // k-quad
    const int c    = lane & 15;

    // ---- stage ALL W' slots once (4608 chunks of 16 B, linear 1:1)
#pragma unroll
    for (int i = 0; i < 18; i++) {
        int p = t + i * 256;                    // chunk 0..4607
        *(short8v*)&wlds[(size_t)p * 8] = *(const short8v*)&wfrag[(size_t)p * 8];
    }
    __syncthreads();

    // ---- barrier-free tile loop
    for (int tile = blockIdx.x; tile < ntiles; tile += gridDim.x) {
        const int n0  = tile * 64;
        const int row = n0 + wave * 16 + c;
        const int rc  = row < N ? row : N - 1;
        const float* ap = feat + (size_t)rc * 256 + g * 8;

        float4 a4[16];
#pragma unroll
        for (int ks = 0; ks < 8; ks++) {
            a4[2 * ks]     = *(const float4*)(ap + ks * 32);
            a4[2 * ks + 1] = *(const float4*)(ap + ks * 32 + 4);
        }

        f32x4 acc[9];
#pragma unroll
        for (int nt = 0; nt < 9; nt++) acc[nt] = (f32x4){0.f, 0.f, 0.f, 0.f};

#pragma unroll
        for (int ks = 0; ks < 8; ks++) {
            float4 v0 = a4[2 * ks], v1 = a4[2 * ks + 1];
            short s8[8];
            s8[0] = (short)f2bf(v0.x); s8[1] = (short)f2bf(v0.y);
            s8[2] = (short)f2bf(v0.z); s8[3] = (short)f2bf(v0.w);
            s8[4] = (short)f2bf(v1.x); s8[5] = (short)f2bf(v1.y);
            s8[6] = (short)f2bf(v1.z); s8[7] = (short)f2bf(v1.w);
            short8v afrag = *(short8v*)s8;
#pragma unroll
            for (int nt = 0; nt < 9; nt++) {
                short8v b = *(short8v*)&wlds[(((size_t)ks * 9 + nt) * 64 + lane) * 8];
                acc[nt] = __builtin_amdgcn_mfma_f32_16x16x32_bf16(afrag, b, acc[nt], 0, 0, 0);
            }
        }

        // ---- epilogue: C/D layout col = nt*16 + c, row = wave*16 + g*4 + r
#pragma unroll
        for (int r = 0; r < 4; r++) {
            int m = n0 + wave * 16 + g * 4 + r;
            if (m < N) {
#pragma unroll
                for (int nt = 0; nt < 8; nt++)
                    hb[(size_t)m * 128 + nt * 16 + c] = f2bf(acc[nt][r]);
                float av = acc[8][r];
                if (c < 4)      el[(size_t)m * 4 + c]       = av;
                else if (c < 8) er[(size_t)m * 4 + (c - 4)] = av;
            }
        }
    }

    // ---- fused bucket histogram (slice of 2048 edges per block)
    if ((size_t)blockIdx.x * BIN_EDGES < (size_t)E) {
        for (int i = t; i < 512; i += 256) bh[i] = 0;
        __syncthreads();
        int base = blockIdx.x * BIN_EDGES + t;
#pragma unroll
        for (int k = 0; k < GEMM_EPT; k++) {
            int idx = base + k * 256;
            if (idx < E) atomicAdd(&bh[dst[idx] >> NPB_SHIFT], 1);
        }
        __syncthreads();
        for (int i = t; i < NB; i += 256) {
            int h = bh[i];
            if (h) atomicAdd(&bcount[i], h);
        }
    }
}

// single-WG scan of bucket counts -> bucket bases + cursors; also start[N]=E
__global__ __launch_bounds__(512) void k_bscan(const int* __restrict__ bcount,
                                               int* __restrict__ bbase,
                                               int* __restrict__ bcur,
                                               int* __restrict__ startA,
                                               int NB, int N) {
    __shared__ int s[512];
    int t = threadIdx.x;
    int h = (t < NB) ? bcount[t] : 0;
    s[t] = h;
    __syncthreads();
    for (int off = 1; off < 512; off <<= 1) {
        int v = (t >= off) ? s[t - off] : 0;
        __syncthreads();
        s[t] += v;
        __syncthreads();
    }
    int excl = s[t] - h;
    if (t <= NB) bbase[t] = excl;     // bbase[NB] = E
    if (t < NB)  bcur[t]  = excl;
    if (t == 0)  startA[N] = s[511];  // total = E
}

// scatter edges into bucket-contiguous order, packed src|ldst<<24 (4 B/edge).
// 512 threads / 2048 edges per WG -> 489 WGs; LDS-reorder so global writes
// are coalesced runs.
__global__ __launch_bounds__(512) void k_binscatter(const int* __restrict__ src,
                                                    const int* __restrict__ dst,
                                                    int* __restrict__ bcur,
                                                    unsigned int* __restrict__ binned,
                                                    int E, int NB) {
    __shared__ int hist[512];
    __shared__ int scn[512];
    __shared__ int lcur[512];
    __shared__ int gdelta[512];
    __shared__ int ebuf[BIN_EDGES];   // 8 KB: src per local slot
    __shared__ int dbuf[BIN_EDGES];   // 8 KB: dst per local slot
    int t = threadIdx.x;
    hist[t] = 0;
    __syncthreads();
    int wbase = blockIdx.x * BIN_EDGES;
    int base  = wbase + t;
    int ne    = E - wbase; if (ne > BIN_EDGES) ne = BIN_EDGES;
    int sv[BS_EPT], dv[BS_EPT];
#pragma unroll
    for (int k = 0; k < BS_EPT; k++) {
        int idx = base + k * 512;
        if (idx < E) {
            sv[k] = src[idx];
            dv[k] = dst[idx];
            atomicAdd(&hist[dv[k] >> NPB_SHIFT], 1);
        } else {
            dv[k] = -1;
        }
    }
    __syncthreads();
    // inclusive scan of 512 counts with 512 threads (Hillis-Steele)
    scn[t] = hist[t];
    __syncthreads();
    for (int off = 1; off < 512; off <<= 1) {
        int v = (t >= off) ? scn[t - off] : 0;
        __syncthreads();
        scn[t] += v;
        __syncthreads();
    }
    // claim global ranges; set local cursors
    if (t < NB) {
        int h  = hist[t];
        int lb = scn[t] - h;
        int g  = h ? atomicAdd(&bcur[t], h) : 0;
        gdelta[t] = g - lb;
        lcur[t]   = lb;
    }
    __syncthreads();
    // local scatter into bucket-sorted LDS order
#pragma unroll
    for (int k = 0; k < BS_EPT; k++) {
        if (dv[k] >= 0) {
            int bkt  = dv[k] >> NPB_SHIFT;
            int slot = atomicAdd(&lcur[bkt], 1);
            ebuf[slot] = sv[k];
            dbuf[slot] = dv[k];
        }
    }
    __syncthreads();
    // linear write-out: address = slot + gdelta[bucket]  (coalesced runs)
    for (int j = t; j < ne; j += 512) {
        int d = dbuf[j];
        binned[j + gdelta[d >> NPB_SHIFT]] =
            (unsigned int)ebuf[j] | ((unsigned int)(d & 255) << 24);
    }
}

// one WG per bucket: degree hist -> start, then LDS-stage the node-sorted
// edges and write the bucket's CSR segment with one linear coalesced pass.
__global__ __launch_bounds__(512) void k_csr(const unsigned int* __restrict__ binned,
                                             const int* __restrict__ bbase,
                                             int* __restrict__ startA,
                                             int* __restrict__ src_csr, int N) {
    __shared__ int hist[256];
    __shared__ int scn[256];
    __shared__ int cur[256];
    __shared__ int sbuf[4096];   // 16 KB staging (max bucket ~2.8K edges expected)
    int b = blockIdx.x;
    int t = threadIdx.x;
    int base = bbase[b];
    int cnt  = bbase[b + 1] - base;
    int node0 = b << NPB_SHIFT;
    if (t < 256) hist[t] = 0;
    __syncthreads();
    for (int i = t; i < cnt; i += 512) {
        unsigned int e = binned[base + i];
        atomicAdd(&hist[e >> 24], 1);
    }
    __syncthreads();
    int h = (t < 256) ? hist[t] : 0;
    if (t < 256) scn[t] = h;
    __syncthreads();
    for (int off = 1; off < 256; off <<= 1) {
        int v = (t < 256 && t >= off) ? scn[t - off] : 0;
        __syncthreads();
        if (t < 256) scn[t] += v;
        __syncthreads();
    }
    if (t < 256) {
        int excl  = scn[t] - h;
        int gnode = node0 + t;
        if (gnode < N) startA[gnode] = base + excl;
        cur[t] = excl;
    }
    __syncthreads();
    if (cnt <= 4096) {
        for (int i = t; i < cnt; i += 512) {
            unsigned int e = binned[base + i];
            int p = atomicAdd(&cur[e >> 24], 1);
            sbuf[p] = (int)(e & 0xFFFFFFu);
        }
        __syncthreads();
        for (int i = t; i < cnt; i += 512)
            src_csr[base + i] = sbuf[i];
    } else {
        // fallback: direct scatter (degenerate distributions only)
        for (int i = t; i < cnt; i += 512) {
            unsigned int e = binned[base + i];
            int p = atomicAdd(&cur[e >> 24], 1);
            src_csr[base + p] = (int)(e & 0xFFFFFFu);
        }
    }
}

// ---------------- gather-side aggregation: one wave per dst node -------------
// unroll-8 with batched index/gather issue (8 outstanding 256-B gathers per
// wave) to hide LLC-hit latency; degree from start[w+1]-start[w].
__global__ __launch_bounds__(256) void k_agg(
        const unsigned int* __restrict__ hbu,
        const float* __restrict__ el, const float* __restrict__ er,
        const int* __restrict__ src_csr, const int* __restrict__ start,
        const float* __restrict__ bias, float* __restrict__ out, int N) {
    int wid  = blockIdx.x * 4 + (threadIdx.x >> 6);
    int lane = threadIdx.x & 63;
    if (wid >= N) return;
    int beg = __builtin_amdgcn_readfirstlane(start[wid]);
    int end = __builtin_amdgcn_readfirstlane(start[wid + 1]);
    int dg  = end - beg;
    int head = lane >> 4;   // elements (2*lane, 2*lane+1) share one head

    float er_own = er[(size_t)wid * 4 + head];   // wave-uniform per 16-lane group
    unsigned int uh = hbu[(size_t)wid * 64 + lane];  // own row, issued early
    float2 bv = ((const float2*)bias)[lane];

    float S1x = 0.f, S1y = 0.f, S2x = 0.f, S2y = 0.f, dd = 0.f;
    int i = 0;
    for (; i + 8 <= dg; i += 8) {
        int b = beg + i;
        int s[8];
#pragma unroll
        for (int k = 0; k < 8; k++) s[k] = src_csr[b + k];
        unsigned int u[8];
#pragma unroll
        for (int k = 0; k < 8; k++) u[k] = hbu[(size_t)s[k] * 64 + lane];
        float ev[8];
#pragma unroll
        for (int k = 0; k < 8; k++) ev[k] = el[(size_t)s[k] * 4 + head];
#pragma unroll
        for (int k = 0; k < 8; k++) {
            float tt = ev[k] + er_own;
            tt = fmaxf(tt, NEG_SLOPE * tt);
            float w = __expf(tt);
            float x = uas(u[k] << 16), y = uas(u[k] & 0xFFFF0000u);
            S1x += x; S1y += y;
            S2x += w * x; S2y += w * y;
            dd  += w;
        }
    }
    for (; i + 4 <= dg; i += 4) {
        int b = beg + i;
        int s[4];
#pragma unroll
        for (int k = 0; k < 4; k++) s[k] = src_csr[b + k];
        unsigned int u[4];
#pragma unroll
        for (int k = 0; k < 4; k++) u[k] = hbu[(size_t)s[k] * 64 + lane];
        float ev[4];
#pragma unroll
        for (int k = 0; k < 4; k++) ev[k] = el[(size_t)s[k] * 4 + head];
#pragma unroll
        for (int k = 0; k < 4; k++) {
            float tt = ev[k] + er_own;
            tt = fmaxf(tt, NEG_SLOPE * tt);
            float w = __expf(tt);
            float x = uas(u[k] << 16), y = uas(u[k] & 0xFFFF0000u);
            S1x += x; S1y += y;
            S2x += w * x; S2y += w * y;
            dd  += w;
        }
    }
    for (; i < dg; i++) {
        int s0 = src_csr[beg + i];
        unsigned int u0 = hbu[(size_t)s0 * 64 + lane];
        float tt = el[(size_t)s0 * 4 + head] + er_own;
        tt = fmaxf(tt, NEG_SLOPE * tt);
        float w0 = __expf(tt);
        float x0 = uas(u0 << 16), y0 = uas(u0 & 0xFFFF0000u);
        S1x += x0; S1y += y0;
        S2x += w0 * x0; S2y += w0 * y0;
        dd  += w0;
    }

    float hvx = uas(uh << 16), hvy = uas(uh & 0xFFFF0000u);
    float inv = dd > 0.f ? 1.f / dd : 0.f;
    float ox = bv.x + hvx * S1x + S2x * inv;
    float oy = bv.y + hvy * S1y + S2y * inv;
    float2 o = {ox, oy};
    ((float2*)(out + (size_t)wid * 128))[lane] = o;
}

extern "C" void kernel_launch(void* const* d_in, const int* in_sizes, int n_in,
                              void* d_out, int out_size, void* d_ws, size_t ws_size,
                              hipStream_t stream) {
    const float* feat = (const float*)d_in[0];
    const float* W_fc = (const float*)d_in[1];
    const float* al   = (const float*)d_in[2];
    const float* ar   = (const float*)d_in[3];
    const float* bias = (const float*)d_in[4];
    const int*   src  = (const int*)d_in[5];
    const int*   dst  = (const int*)d_in[6];
    const int N = in_sizes[0] / 256;
    const int E = in_sizes[5];
    const int NB = (N + 255) >> NPB_SHIFT;   // <= 512 for N <= 131072

    char* ws = (char*)d_ws;
    size_t off = 0;
    unsigned int* hbu = (unsigned int*)(ws + off); off += (size_t)N * 64 * 4; // 25.6 MB
    float* el         = (float*)(ws + off); off += (size_t)N * 4 * 4;         // 1.6 MB
    float* er         = (float*)(ws + off); off += (size_t)N * 4 * 4;         // 1.6 MB
    int* startA       = (int*)(ws + off);   off += (size_t)(N + 1) * 4;
    int* src_csr      = (int*)(ws + off);   off += (size_t)E * 4;             // 4 MB
    unsigned int* binned = (unsigned int*)(ws + off); off += (size_t)E * 4;   // 4 MB
    short* wfrag      = (short*)(ws + off); off += (size_t)72 * 64 * 8 * 2;   // 72 KB
    int* bcount       = (int*)(ws + off);   off += 2048;
    int* bbase        = (int*)(ws + off);   off += 2064;                      // NB+1
    int* bcur         = (int*)(ws + off);   off += 2048;

    float* out = (float*)d_out;

    int ntiles = (N + 63) / 64;
    int binWG  = (E + BIN_EDGES - 1) / BIN_EDGES;
    int gemmWG = GEMM_BLOCKS > binWG ? GEMM_BLOCKS : binWG;  // cover hist slices

    k_prep<<<18, 256, 0, stream>>>(W_fc, al, ar, wfrag, bcount, NB);
    k_gemm<<<gemmWG, 256, 0, stream>>>(feat, wfrag, (unsigned short*)hbu,
                                       el, er, N, ntiles, dst, bcount, E, NB);
    k_bscan<<<1, 512, 0, stream>>>(bcount, bbase, bcur, startA, NB, N);
    k_binscatter<<<binWG, 512, 0, stream>>>(src, dst, bcur, binned, E, NB);
    k_csr<<<NB, 512, 0, stream>>>(binned, bbase, startA, src_csr, N);
    k_agg<<<(N + 3) / 4, 256, 0, stream>>>(hbu, el, er, src_csr, startA,
                                           bias, out, N);
}

// Round 8
// 274.669 us; speedup vs baseline: 1.0666x; 1.0228x over previous
//
#include <hip/hip_runtime.h>
#include <hip/hip_bf16.h>
#include <hip/hip_fp16.h>
#include <math.h>

#define NEG_SLOPE 0.2f

typedef __attribute__((ext_vector_type(8))) short short8v;
typedef __attribute__((ext_vector_type(4))) float f32x4;

__device__ __forceinline__ float uas(unsigned int u) { return __uint_as_float(u); }

__device__ __forceinline__ unsigned short f2bf(float x) {
    __hip_bfloat16 b = __float2bfloat16(x);
    return *(unsigned short*)&b;
}

#define NPB_SHIFT 8
#define BIN_EDGES 2048            // edges per histogram/scatter slice
#define GEMM_EPT  4               // 2048 / 512 threads (gemm fused hist)
#define BS_EPT    4               // 2048 / 512 threads (binscatter)
#define GEMM_BLOCKS 512           // persistent blocks (2 per CU)

// ---------------- W prep: extended bf16 fragment image -----------------------
// Extended B matrix W'[144,256]: rows 0..127 = W; rows 128..135 = head-masked
// attn projections vl[4],vr[4]; rows 136..143 = 0.  Also zeroes bcount.
__global__ void k_prep(const float* __restrict__ W, const float* __restrict__ al,
                       const float* __restrict__ ar, short* __restrict__ wfrag,
                       int* __restrict__ bcount, int NB) {
    int p = blockIdx.x * 256 + threadIdx.x;   // n*32+kg, 0..4607
    if (p < NB) bcount[p] = 0;
    if (p >= 144 * 32) return;
    int n = p >> 5, kg = p & 31;
    float v[8];
    if (n < 128) {
        const float* wp = W + (size_t)n * 256 + kg * 8;
        float4 v0 = *(const float4*)wp;
        float4 v1 = *(const float4*)(wp + 4);
        v[0] = v0.x; v[1] = v0.y; v[2] = v0.z; v[3] = v0.w;
        v[4] = v1.x; v[5] = v1.y; v[6] = v1.z; v[7] = v1.w;
    } else if (n < 136) {
        int i = n - 128, hh = i & 3, lr = i >> 2;
        const float* av = lr ? ar : al;
#pragma unroll
        for (int j = 0; j < 8; j++) v[j] = 0.f;
        for (int c = 0; c < 32; c++) {
            float a = av[hh * 32 + c];
            const float* wp = W + (size_t)(hh * 32 + c) * 256 + kg * 8;
#pragma unroll
            for (int j = 0; j < 8; j++) v[j] += a * wp[j];
        }
    } else {
#pragma unroll
        for (int j = 0; j < 8; j++) v[j] = 0.f;
    }
    short s8[8];
#pragma unroll
    for (int j = 0; j < 8; j++) s8[j] = (short)f2bf(v[j]);
    int kstep = kg >> 2, ntile = n >> 4;
    int L     = (kg & 3) * 16 + (n & 15);
    int slot  = kstep * 9 + ntile;
    *(short8v*)&wfrag[(slot * 64 + L) * 8] = *(short8v*)s8;
}

// ---------------- MFMA GEMM + fused el/er + fused bucket histogram -----------
// v4: persistent 512-THREAD blocks (8 waves, 128-row tiles).  LDS/block is
// pinned at 74 KB by the B-image (2 blocks/CU); doubling threads/block at
// constant LDS doubles resident waves to 16/CU (50% cap) -- the extra TLP
// hides the per-wave A-load HBM latency that rounds 5/7 exposed at 8 waves.
__global__ __launch_bounds__(512) void k_gemm(const float* __restrict__ feat,
                                              const short* __restrict__ wfrag,
                                              unsigned short* __restrict__ hb,
                                              float* __restrict__ el,
                                              float* __restrict__ er, int N,
                                              int ntiles,
                                              const int* __restrict__ dst,
                                              int* __restrict__ bcount,
                                              int E, int NB) {
    __shared__ short wlds[36864];   // 72 KB: all 72 slots, linear
    __shared__ int bh[512];         // bucket histogram
    const int t    = threadIdx.x;
    const int lane = t & 63;
    const int wave = t >> 6;        // 0..7
    const int g    = lane >> 4;     // k-quad
    const int c    = lane & 15;

    // ---- stage ALL W' slots once (4608 chunks of 16 B, linear 1:1)
#pragma unroll
    for (int i = 0; i < 9; i++) {
        int p = t + i * 512;                    // chunk 0..4607
        *(short8v*)&wlds[(size_t)p * 8] = *(const short8v*)&wfrag[(size_t)p * 8];
    }
    __syncthreads();

    // ---- barrier-free tile loop (128 rows per tile, 16 per wave)
    for (int tile = blockIdx.x; tile < ntiles; tile += gridDim.x) {
        const int n0  = tile * 128;
        const int row = n0 + wave * 16 + c;
        const int rc  = row < N ? row : N - 1;
        const float* ap = feat + (size_t)rc * 256 + g * 8;

        float4 a4[16];
#pragma unroll
        for (int ks = 0; ks < 8; ks++) {
            a4[2 * ks]     = *(const float4*)(ap + ks * 32);
            a4[2 * ks + 1] = *(const float4*)(ap + ks * 32 + 4);
        }

        f32x4 acc[9];
#pragma unroll
        for (int nt = 0; nt < 9; nt++) acc[nt] = (f32x4){0.f, 0.f, 0.f, 0.f};

#pragma unroll
        for (int ks = 0; ks < 8; ks++) {
            float4 v0 = a4[2 * ks], v1 = a4[2 * ks + 1];
            short s8[8];
            s8[0] = (short)f2bf(v0.x); s8[1] = (short)f2bf(v0.y);
            s8[2] = (short)f2bf(v0.z); s8[3] = (short)f2bf(v0.w);
            s8[4] = (short)f2bf(v1.x); s8[5] = (short)f2bf(v1.y);
            s8[6] = (short)f2bf(v1.z); s8[7] = (short)f2bf(v1.w);
            short8v afrag = *(short8v*)s8;
#pragma unroll
            for (int nt = 0; nt < 9; nt++) {
                short8v b = *(short8v*)&wlds[(((size_t)ks * 9 + nt) * 64 + lane) * 8];
                acc[nt] = __builtin_amdgcn_mfma_f32_16x16x32_bf16(afrag, b, acc[nt], 0, 0, 0);
            }
        }

        // ---- epilogue: C/D layout col = nt*16 + c, row = wave*16 + g*4 + r
#pragma unroll
        for (int r = 0; r < 4; r++) {
            int m = n0 + wave * 16 + g * 4 + r;
            if (m < N) {
#pragma unroll
                for (int nt = 0; nt < 8; nt++)
                    hb[(size_t)m * 128 + nt * 16 + c] = f2bf(acc[nt][r]);
                float av = acc[8][r];
                if (c < 4)      el[(size_t)m * 4 + c]       = av;
                else if (c < 8) er[(size_t)m * 4 + (c - 4)] = av;
            }
        }
    }

    // ---- fused bucket histogram (slice of 2048 edges per block)
    if ((size_t)blockIdx.x * BIN_EDGES < (size_t)E) {
        if (t < 512) bh[t] = 0;
        __syncthreads();
        int base = blockIdx.x * BIN_EDGES + t;
#pragma unroll
        for (int k = 0; k < GEMM_EPT; k++) {
            int idx = base + k * 512;
            if (idx < E) atomicAdd(&bh[dst[idx] >> NPB_SHIFT], 1);
        }
        __syncthreads();
        for (int i = t; i < NB; i += 512) {
            int h = bh[i];
            if (h) atomicAdd(&bcount[i], h);
        }
    }
}

// single-WG scan of bucket counts -> bucket bases + cursors; also start[N]=E
__global__ __launch_bounds__(512) void k_bscan(const int* __restrict__ bcount,
                                               int* __restrict__ bbase,
                                               int* __restrict__ bcur,
                                               int* __restrict__ startA,
                                               int NB, int N) {
    __shared__ int s[512];
    int t = threadIdx.x;
    int h = (t < NB) ? bcount[t] : 0;
    s[t] = h;
    __syncthreads();
    for (int off = 1; off < 512; off <<= 1) {
        int v = (t >= off) ? s[t - off] : 0;
        __syncthreads();
        s[t] += v;
        __syncthreads();
    }
    int excl = s[t] - h;
    if (t <= NB) bbase[t] = excl;     // bbase[NB] = E
    if (t < NB)  bcur[t]  = excl;
    if (t == 0)  startA[N] = s[511];  // total = E
}

// scatter edges into bucket-contiguous order, packed src|ldst<<24 (4 B/edge).
// 512 threads / 2048 edges per WG -> 489 WGs; LDS-reorder so global writes
// are coalesced runs.
__global__ __launch_bounds__(512) void k_binscatter(const int* __restrict__ src,
                                                    const int* __restrict__ dst,
                                                    int* __restrict__ bcur,
                                                    unsigned int* __restrict__ binned,
                                                    int E, int NB) {
    __shared__ int hist[512];
    __shared__ int scn[512];
    __shared__ int lcur[512];
    __shared__ int gdelta[512];
    __shared__ int ebuf[BIN_EDGES];   // 8 KB: src per local slot
    __shared__ int dbuf[BIN_EDGES];   // 8 KB: dst per local slot
    int t = threadIdx.x;
    hist[t] = 0;
    __syncthreads();
    int wbase = blockIdx.x * BIN_EDGES;
    int base  = wbase + t;
    int ne    = E - wbase; if (ne > BIN_EDGES) ne = BIN_EDGES;
    int sv[BS_EPT], dv[BS_EPT];
#pragma unroll
    for (int k = 0; k < BS_EPT; k++) {
        int idx = base + k * 512;
        if (idx < E) {
            sv[k] = src[idx];
            dv[k] = dst[idx];
            atomicAdd(&hist[dv[k] >> NPB_SHIFT], 1);
        } else {
            dv[k] = -1;
        }
    }
    __syncthreads();
    // inclusive scan of 512 counts with 512 threads (Hillis-Steele)
    scn[t] = hist[t];
    __syncthreads();
    for (int off = 1; off < 512; off <<= 1) {
        int v = (t >= off) ? scn[t - off] : 0;
        __syncthreads();
        scn[t] += v;
        __syncthreads();
    }
    // claim global ranges; set local cursors
    if (t < NB) {
        int h  = hist[t];
        int lb = scn[t] - h;
        int g  = h ? atomicAdd(&bcur[t], h) : 0;
        gdelta[t] = g - lb;
        lcur[t]   = lb;
    }
    __syncthreads();
    // local scatter into bucket-sorted LDS order
#pragma unroll
    for (int k = 0; k < BS_EPT; k++) {
        if (dv[k] >= 0) {
            int bkt  = dv[k] >> NPB_SHIFT;
            int slot = atomicAdd(&lcur[bkt], 1);
            ebuf[slot] = sv[k];
            dbuf[slot] = dv[k];
        }
    }
    __syncthreads();
    // linear write-out: address = slot + gdelta[bucket]  (coalesced runs)
    for (int j = t; j < ne; j += 512) {
        int d = dbuf[j];
        binned[j + gdelta[d >> NPB_SHIFT]] =
            (unsigned int)ebuf[j] | ((unsigned int)(d & 255) << 24);
    }
}

// one WG per bucket: degree hist -> start, then LDS-stage the node-sorted
// edges and write the bucket's CSR segment with one linear coalesced pass.
__global__ __launch_bounds__(512) void k_csr(const unsigned int* __restrict__ binned,
                                             const int* __restrict__ bbase,
                                             int* __restrict__ startA,
                                             int* __restrict__ src_csr, int N) {
    __shared__ int hist[256];
    __shared__ int scn[256];
    __shared__ int cur[256];
    __shared__ int sbuf[4096];   // 16 KB staging (max bucket ~2.8K edges expected)
    int b = blockIdx.x;
    int t = threadIdx.x;
    int base = bbase[b];
    int cnt  = bbase[b + 1] - base;
    int node0 = b << NPB_SHIFT;
    if (t < 256) hist[t] = 0;
    __syncthreads();
    for (int i = t; i < cnt; i += 512) {
        unsigned int e = binned[base + i];
        atomicAdd(&hist[e >> 24], 1);
    }
    __syncthreads();
    int h = (t < 256) ? hist[t] : 0;
    if (t < 256) scn[t] = h;
    __syncthreads();
    for (int off = 1; off < 256; off <<= 1) {
        int v = (t < 256 && t >= off) ? scn[t - off] : 0;
        __syncthreads();
        if (t < 256) scn[t] += v;
        __syncthreads();
    }
    if (t < 256) {
        int excl  = scn[t] - h;
        int gnode = node0 + t;
        if (gnode < N) startA[gnode] = base + excl;
        cur[t] = excl;
    }
    __syncthreads();
    if (cnt <= 4096) {
        for (int i = t; i < cnt; i += 512) {
            unsigned int e = binned[base + i];
            int p = atomicAdd(&cur[e >> 24], 1);
            sbuf[p] = (int)(e & 0xFFFFFFu);
        }
        __syncthreads();
        for (int i = t; i < cnt; i += 512)
            src_csr[base + i] = sbuf[i];
    } else {
        // fallback: direct scatter (degenerate distributions only)
        for (int i = t; i < cnt; i += 512) {
            unsigned int e = binned[base + i];
            int p = atomicAdd(&cur[e >> 24], 1);
            src_csr[base + p] = (int)(e & 0xFFFFFFu);
        }
    }
}

// ---------------- gather-side aggregation: one wave per dst node -------------
// unroll-8 with batched index/gather issue (8 outstanding 256-B gathers per
// wave) to hide LLC-hit latency; degree from start[w+1]-start[w].
__global__ __launch_bounds__(256) void k_agg(
        const unsigned int* __restrict__ hbu,
        const float* __restrict__ el, const float* __restrict__ er,
        const int* __restrict__ src_csr, const int* __restrict__ start,
        const float* __restrict__ bias, float* __restrict__ out, int N) {
    int wid  = blockIdx.x * 4 + (threadIdx.x >> 6);
    int lane = threadIdx.x & 63;
    if (wid >= N) return;
    int beg = __builtin_amdgcn_readfirstlane(start[wid]);
    int end = __builtin_amdgcn_readfirstlane(start[wid + 1]);
    int dg  = end - beg;
    int head = lane >> 4;   // elements (2*lane, 2*lane+1) share one head

    float er_own = er[(size_t)wid * 4 + head];   // wave-uniform per 16-lane group
    unsigned int uh = hbu[(size_t)wid * 64 + lane];  // own row, issued early
    float2 bv = ((const float2*)bias)[lane];

    float S1x = 0.f, S1y = 0.f, S2x = 0.f, S2y = 0.f, dd = 0.f;
    int i = 0;
    for (; i + 8 <= dg; i += 8) {
        int b = beg + i;
        int s[8];
#pragma unroll
        for (int k = 0; k < 8; k++) s[k] = src_csr[b + k];
        unsigned int u[8];
#pragma unroll
        for (int k = 0; k < 8; k++) u[k] = hbu[(size_t)s[k] * 64 + lane];
        float ev[8];
#pragma unroll
        for (int k = 0; k < 8; k++) ev[k] = el[(size_t)s[k] * 4 + head];
#pragma unroll
        for (int k = 0; k < 8; k++) {
            float tt = ev[k] + er_own;
            tt = fmaxf(tt, NEG_SLOPE * tt);
            float w = __expf(tt);
            float x = uas(u[k] << 16), y = uas(u[k] & 0xFFFF0000u);
            S1x += x; S1y += y;
            S2x += w * x; S2y += w * y;
            dd  += w;
        }
    }
    for (; i + 4 <= dg; i += 4) {
        int b = beg + i;
        int s[4];
#pragma unroll
        for (int k = 0; k < 4; k++) s[k] = src_csr[b + k];
        unsigned int u[4];
#pragma unroll
        for (int k = 0; k < 4; k++) u[k] = hbu[(size_t)s[k] * 64 + lane];
        float ev[4];
#pragma unroll
        for (int k = 0; k < 4; k++) ev[k] = el[(size_t)s[k] * 4 + head];
#pragma unroll
        for (int k = 0; k < 4; k++) {
            float tt = ev[k] + er_own;
            tt = fmaxf(tt, NEG_SLOPE * tt);
            float w = __expf(tt);
            float x = uas(u[k] << 16), y = uas(u[k] & 0xFFFF0000u);
            S1x += x; S1y += y;
            S2x += w * x; S2y += w * y;
            dd  += w;
        }
    }
    for (; i < dg; i++) {
        int s0 = src_csr[beg + i];
        unsigned int u0 = hbu[(size_t)s0 * 64 + lane];
        float tt = el[(size_t)s0 * 4 + head] + er_own;
        tt = fmaxf(tt, NEG_SLOPE * tt);
        float w0 = __expf(tt);
        float x0 = uas(u0 << 16), y0 = uas(u0 & 0xFFFF0000u);
        S1x += x0; S1y += y0;
        S2x += w0 * x0; S2y += w0 * y0;
        dd  += w0;
    }

    float hvx = uas(uh << 16), hvy = uas(uh & 0xFFFF0000u);
    float inv = dd > 0.f ? 1.f / dd : 0.f;
    float ox = bv.x + hvx * S1x + S2x * inv;
    float oy = bv.y + hvy * S1y + S2y * inv;
    float2 o = {ox, oy};
    ((float2*)(out + (size_t)wid * 128))[lane] = o;
}

extern "C" void kernel_launch(void* const* d_in, const int* in_sizes, int n_in,
                              void* d_out, int out_size, void* d_ws, size_t ws_size,
                              hipStream_t stream) {
    const float* feat = (const float*)d_in[0];
    const float* W_fc = (const float*)d_in[1];
    const float* al   = (const float*)d_in[2];
    const float* ar   = (const float*)d_in[3];
    const float* bias = (const float*)d_in[4];
    const int*   src  = (const int*)d_in[5];
    const int*   dst  = (const int*)d_in[6];
    const int N = in_sizes[0] / 256;
    const int E = in_sizes[5];
    const int NB = (N + 255) >> NPB_SHIFT;   // <= 512 for N <= 131072

    char* ws = (char*)d_ws;
    size_t off = 0;
    unsigned int* hbu = (unsigned int*)(ws + off); off += (size_t)N * 64 * 4; // 25.6 MB
    float* el         = (float*)(ws + off); off += (size_t)N * 4 * 4;         // 1.6 MB
    float* er         = (float*)(ws + off); off += (size_t)N * 4 * 4;         // 1.6 MB
    int* startA       = (int*)(ws + off);   off += (size_t)(N + 1) * 4;
    int* src_csr      = (int*)(ws + off);   off += (size_t)E * 4;             // 4 MB
    unsigned int* binned = (unsigned int*)(ws + off); off += (size_t)E * 4;   // 4 MB
    short* wfrag      = (short*)(ws + off); off += (size_t)72 * 64 * 8 * 2;   // 72 KB
    int* bcount       = (int*)(ws + off);   off += 2048;
    int* bbase        = (int*)(ws + off);   off += 2064;                      // NB+1
    int* bcur         = (int*)(ws + off);   off += 2048;

    float* out = (float*)d_out;

    int ntiles = (N + 127) / 128;
    int binWG  = (E + BIN_EDGES - 1) / BIN_EDGES;
    int gemmWG = GEMM_BLOCKS > binWG ? GEMM_BLOCKS : binWG;  // cover hist slices

    k_prep<<<18, 256, 0, stream>>>(W_fc, al, ar, wfrag, bcount, NB);
    k_gemm<<<gemmWG, 512, 0, stream>>>(feat, wfrag, (unsigned short*)hbu,
                                       el, er, N, ntiles, dst, bcount, E, NB);
    k_bscan<<<1, 512, 0, stream>>>(bcount, bbase, bcur, startA, NB, N);
    k_binscatter<<<binWG, 512, 0, stream>>>(src, dst, bcur, binned, E, NB);
    k_csr<<<NB, 512, 0, stream>>>(binned, bbase, startA, src_csr, N);
    k_agg<<<(N + 3) / 4, 256, 0, stream>>>(hbu, el, er, src_csr, startA,
                                           bias, out, N);
}

// Round 9
// 272.047 us; speedup vs baseline: 1.0768x; 1.0096x over previous
//
#include <hip/hip_runtime.h>
#include <hip/hip_bf16.h>
#include <hip/hip_fp16.h>
#include <math.h>

#define NEG_SLOPE 0.2f

typedef __attribute__((ext_vector_type(8))) short short8v;
typedef __attribute__((ext_vector_type(4))) float f32x4;

__device__ __forceinline__ float uas(unsigned int u) { return __uint_as_float(u); }

__device__ __forceinline__ unsigned short f2bf(float x) {
    __hip_bfloat16 b = __float2bfloat16(x);
    return *(unsigned short*)&b;
}

#define NPB_SHIFT 8
#define BIN_EDGES 2048            // edges per histogram/scatter slice
#define GEMM_EPT  4               // 2048 / 512 threads (gemm fused hist)
#define BS_EPT    4               // 2048 / 512 threads (binscatter)
#define GEMM_BLOCKS 512           // persistent blocks (2 per CU)

// ---------------- W prep: extended bf16 fragment image -----------------------
// Extended B matrix W'[144,256]: rows 0..127 = W; rows 128..135 = head-masked
// attn projections vl[4],vr[4]; rows 136..143 = 0.  Also zeroes bcount and
// the gemm tile counter.
__global__ void k_prep(const float* __restrict__ W, const float* __restrict__ al,
                       const float* __restrict__ ar, short* __restrict__ wfrag,
                       int* __restrict__ bcount, int NB, int* __restrict__ tilectr) {
    int p = blockIdx.x * 256 + threadIdx.x;   // n*32+kg, 0..4607
    if (p < NB) bcount[p] = 0;
    if (p == 0) *tilectr = 0;
    if (p >= 144 * 32) return;
    int n = p >> 5, kg = p & 31;
    float v[8];
    if (n < 128) {
        const float* wp = W + (size_t)n * 256 + kg * 8;
        float4 v0 = *(const float4*)wp;
        float4 v1 = *(const float4*)(wp + 4);
        v[0] = v0.x; v[1] = v0.y; v[2] = v0.z; v[3] = v0.w;
        v[4] = v1.x; v[5] = v1.y; v[6] = v1.z; v[7] = v1.w;
    } else if (n < 136) {
        int i = n - 128, hh = i & 3, lr = i >> 2;
        const float* av = lr ? ar : al;
#pragma unroll
        for (int j = 0; j < 8; j++) v[j] = 0.f;
        for (int c = 0; c < 32; c++) {
            float a = av[hh * 32 + c];
            const float* wp = W + (size_t)(hh * 32 + c) * 256 + kg * 8;
#pragma unroll
            for (int j = 0; j < 8; j++) v[j] += a * wp[j];
        }
    } else {
#pragma unroll
        for (int j = 0; j < 8; j++) v[j] = 0.f;
    }
    short s8[8];
#pragma unroll
    for (int j = 0; j < 8; j++) s8[j] = (short)f2bf(v[j]);
    int kstep = kg >> 2, ntile = n >> 4;
    int L     = (kg & 3) * 16 + (n & 15);
    int slot  = kstep * 9 + ntile;
    *(short8v*)&wfrag[(slot * 64 + L) * 8] = *(short8v*)s8;
}

// ---------------- MFMA GEMM + fused el/er + fused bucket histogram -----------
// v5: persistent 512-thread blocks (8 waves, 128-row tiles), B-image staged
// once (74 KB LDS, 2 blocks/CU = 16 waves/CU).
// launch_bounds(512,4) -> VGPR cap 128 so the FULL 16-deep A-load batch
// (64 VGPR) stays in registers: ONE HBM round-trip per tile instead of the
// ~4 serialized batches the 52-VGPR allocation forced (rounds 5-8 gap).
// Tiles are claimed from a global atomic counter for per-CU load balance.
__global__ __launch_bounds__(512, 4) void k_gemm(const float* __restrict__ feat,
                                                 const short* __restrict__ wfrag,
                                                 unsigned short* __restrict__ hb,
                                                 float* __restrict__ el,
                                                 float* __restrict__ er, int N,
                                                 int ntiles,
                                                 int* __restrict__ tilectr,
                                                 const int* __restrict__ dst,
                                                 int* __restrict__ bcount,
                                                 int E, int NB) {
    __shared__ short wlds[36864];   // 72 KB: all 72 slots, linear
    __shared__ int bh[512];         // bucket histogram
    __shared__ int tsh;             // broadcast tile index
    const int t    = threadIdx.x;
    const int lane = t & 63;
    const int wave = t >> 6;        // 0..7
    const int g    = lane >> 4;     // k-quad
    const int c    = lane & 15;

    // ---- stage ALL W' slots once (4608 chunks of 16 B, linear 1:1)
#pragma unroll
    for (int i = 0; i < 9; i++) {
        int p = t + i * 512;                    // chunk 0..4607
        *(short8v*)&wlds[(size_t)p * 8] = *(const short8v*)&wfrag[(size_t)p * 8];
    }
    __syncthreads();

    // ---- dynamic tile loop (128 rows per tile, 16 per wave)
    for (;;) {
        if (t == 0) tsh = atomicAdd(tilectr, 1);
        __syncthreads();
        const int tile = tsh;
        __syncthreads();            // all read tsh before next overwrite
        if (tile >= ntiles) break;

        const int n0  = tile * 128;
        const int row = n0 + wave * 16 + c;
        const int rc  = row < N ? row : N - 1;
        const float* ap = feat + (size_t)rc * 256 + g * 8;

        float4 a4[16];
#pragma unroll
        for (int ks = 0; ks < 8; ks++) {
            a4[2 * ks]     = *(const float4*)(ap + ks * 32);
            a4[2 * ks + 1] = *(const float4*)(ap + ks * 32 + 4);
        }

        f32x4 acc[9];
#pragma unroll
        for (int nt = 0; nt < 9; nt++) acc[nt] = (f32x4){0.f, 0.f, 0.f, 0.f};

#pragma unroll
        for (int ks = 0; ks < 8; ks++) {
            float4 v0 = a4[2 * ks], v1 = a4[2 * ks + 1];
            short s8[8];
            s8[0] = (short)f2bf(v0.x); s8[1] = (short)f2bf(v0.y);
            s8[2] = (short)f2bf(v0.z); s8[3] = (short)f2bf(v0.w);
            s8[4] = (short)f2bf(v1.x); s8[5] = (short)f2bf(v1.y);
            s8[6] = (short)f2bf(v1.z); s8[7] = (short)f2bf(v1.w);
            short8v afrag = *(short8v*)s8;
#pragma unroll
            for (int nt = 0; nt < 9; nt++) {
                short8v b = *(short8v*)&wlds[(((size_t)ks * 9 + nt) * 64 + lane) * 8];
                acc[nt] = __builtin_amdgcn_mfma_f32_16x16x32_bf16(afrag, b, acc[nt], 0, 0, 0);
            }
        }

        // ---- epilogue: C/D layout col = nt*16 + c, row = wave*16 + g*4 + r
#pragma unroll
        for (int r = 0; r < 4; r++) {
            int m = n0 + wave * 16 + g * 4 + r;
            if (m < N) {
#pragma unroll
                for (int nt = 0; nt < 8; nt++)
                    hb[(size_t)m * 128 + nt * 16 + c] = f2bf(acc[nt][r]);
                float av = acc[8][r];
                if (c < 4)      el[(size_t)m * 4 + c]       = av;
                else if (c < 8) er[(size_t)m * 4 + (c - 4)] = av;
            }
        }
    }

    // ---- fused bucket histogram (slice of 2048 edges per block)
    if ((size_t)blockIdx.x * BIN_EDGES < (size_t)E) {
        if (t < 512) bh[t] = 0;
        __syncthreads();
        int base = blockIdx.x * BIN_EDGES + t;
#pragma unroll
        for (int k = 0; k < GEMM_EPT; k++) {
            int idx = base + k * 512;
            if (idx < E) atomicAdd(&bh[dst[idx] >> NPB_SHIFT], 1);
        }
        __syncthreads();
        for (int i = t; i < NB; i += 512) {
            int h = bh[i];
            if (h) atomicAdd(&bcount[i], h);
        }
    }
}

// single-WG scan of bucket counts -> bucket bases + cursors; also start[N]=E
__global__ __launch_bounds__(512) void k_bscan(const int* __restrict__ bcount,
                                               int* __restrict__ bbase,
                                               int* __restrict__ bcur,
                                               int* __restrict__ startA,
                                               int NB, int N) {
    __shared__ int s[512];
    int t = threadIdx.x;
    int h = (t < NB) ? bcount[t] : 0;
    s[t] = h;
    __syncthreads();
    for (int off = 1; off < 512; off <<= 1) {
        int v = (t >= off) ? s[t - off] : 0;
        __syncthreads();
        s[t] += v;
        __syncthreads();
    }
    int excl = s[t] - h;
    if (t <= NB) bbase[t] = excl;     // bbase[NB] = E
    if (t < NB)  bcur[t]  = excl;
    if (t == 0)  startA[N] = s[511];  // total = E
}

// scatter edges into bucket-contiguous order, packed src|ldst<<24 (4 B/edge).
// 512 threads / 2048 edges per WG -> 489 WGs; LDS-reorder so global writes
// are coalesced runs.
__global__ __launch_bounds__(512) void k_binscatter(const int* __restrict__ src,
                                                    const int* __restrict__ dst,
                                                    int* __restrict__ bcur,
                                                    unsigned int* __restrict__ binned,
                                                    int E, int NB) {
    __shared__ int hist[512];
    __shared__ int scn[512];
    __shared__ int lcur[512];
    __shared__ int gdelta[512];
    __shared__ int ebuf[BIN_EDGES];   // 8 KB: src per local slot
    __shared__ int dbuf[BIN_EDGES];   // 8 KB: dst per local slot
    int t = threadIdx.x;
    hist[t] = 0;
    __syncthreads();
    int wbase = blockIdx.x * BIN_EDGES;
    int base  = wbase + t;
    int ne    = E - wbase; if (ne > BIN_EDGES) ne = BIN_EDGES;
    int sv[BS_EPT], dv[BS_EPT];
#pragma unroll
    for (int k = 0; k < BS_EPT; k++) {
        int idx = base + k * 512;
        if (idx < E) {
            sv[k] = src[idx];
            dv[k] = dst[idx];
            atomicAdd(&hist[dv[k] >> NPB_SHIFT], 1);
        } else {
            dv[k] = -1;
        }
    }
    __syncthreads();
    // inclusive scan of 512 counts with 512 threads (Hillis-Steele)
    scn[t] = hist[t];
    __syncthreads();
    for (int off = 1; off < 512; off <<= 1) {
        int v = (t >= off) ? scn[t - off] : 0;
        __syncthreads();
        scn[t] += v;
        __syncthreads();
    }
    // claim global ranges; set local cursors
    if (t < NB) {
        int h  = hist[t];
        int lb = scn[t] - h;
        int g  = h ? atomicAdd(&bcur[t], h) : 0;
        gdelta[t] = g - lb;
        lcur[t]   = lb;
    }
    __syncthreads();
    // local scatter into bucket-sorted LDS order
#pragma unroll
    for (int k = 0; k < BS_EPT; k++) {
        if (dv[k] >= 0) {
            int bkt  = dv[k] >> NPB_SHIFT;
            int slot = atomicAdd(&lcur[bkt], 1);
            ebuf[slot] = sv[k];
            dbuf[slot] = dv[k];
        }
    }
    __syncthreads();
    // linear write-out: address = slot + gdelta[bucket]  (coalesced runs)
    for (int j = t; j < ne; j += 512) {
        int d = dbuf[j];
        binned[j + gdelta[d >> NPB_SHIFT]] =
            (unsigned int)ebuf[j] | ((unsigned int)(d & 255) << 24);
    }
}

// one WG per bucket: degree hist -> start, then LDS-stage the node-sorted
// edges and write the bucket's CSR segment with one linear coalesced pass.
__global__ __launch_bounds__(512) void k_csr(const unsigned int* __restrict__ binned,
                                             const int* __restrict__ bbase,
                                             int* __restrict__ startA,
                                             int* __restrict__ src_csr, int N) {
    __shared__ int hist[256];
    __shared__ int scn[256];
    __shared__ int cur[256];
    __shared__ int sbuf[4096];   // 16 KB staging (max bucket ~2.8K edges expected)
    int b = blockIdx.x;
    int t = threadIdx.x;
    int base = bbase[b];
    int cnt  = bbase[b + 1] - base;
    int node0 = b << NPB_SHIFT;
    if (t < 256) hist[t] = 0;
    __syncthreads();
    for (int i = t; i < cnt; i += 512) {
        unsigned int e = binned[base + i];
        atomicAdd(&hist[e >> 24], 1);
    }
    __syncthreads();
    int h = (t < 256) ? hist[t] : 0;
    if (t < 256) scn[t] = h;
    __syncthreads();
    for (int off = 1; off < 256; off <<= 1) {
        int v = (t < 256 && t >= off) ? scn[t - off] : 0;
        __syncthreads();
        if (t < 256) scn[t] += v;
        __syncthreads();
    }
    if (t < 256) {
        int excl  = scn[t] - h;
        int gnode = node0 + t;
        if (gnode < N) startA[gnode] = base + excl;
        cur[t] = excl;
    }
    __syncthreads();
    if (cnt <= 4096) {
        for (int i = t; i < cnt; i += 512) {
            unsigned int e = binned[base + i];
            int p = atomicAdd(&cur[e >> 24], 1);
            sbuf[p] = (int)(e & 0xFFFFFFu);
        }
        __syncthreads();
        for (int i = t; i < cnt; i += 512)
            src_csr[base + i] = sbuf[i];
    } else {
        // fallback: direct scatter (degenerate distributions only)
        for (int i = t; i < cnt; i += 512) {
            unsigned int e = binned[base + i];
            int p = atomicAdd(&cur[e >> 24], 1);
            src_csr[base + p] = (int)(e & 0xFFFFFFu);
        }
    }
}

// ---------------- gather-side aggregation: one wave per dst node -------------
// unroll-8 with batched index/gather issue (8 outstanding 256-B gathers per
// wave) to hide LLC-hit latency; degree from start[w+1]-start[w].
__global__ __launch_bounds__(256) void k_agg(
        const unsigned int* __restrict__ hbu,
        const float* __restrict__ el, const float* __restrict__ er,
        const int* __restrict__ src_csr, const int* __restrict__ start,
        const float* __restrict__ bias, float* __restrict__ out, int N) {
    int wid  = blockIdx.x * 4 + (threadIdx.x >> 6);
    int lane = threadIdx.x & 63;
    if (wid >= N) return;
    int beg = __builtin_amdgcn_readfirstlane(start[wid]);
    int end = __builtin_amdgcn_readfirstlane(start[wid + 1]);
    int dg  = end - beg;
    int head = lane >> 4;   // elements (2*lane, 2*lane+1) share one head

    float er_own = er[(size_t)wid * 4 + head];   // wave-uniform per 16-lane group
    unsigned int uh = hbu[(size_t)wid * 64 + lane];  // own row, issued early
    float2 bv = ((const float2*)bias)[lane];

    float S1x = 0.f, S1y = 0.f, S2x = 0.f, S2y = 0.f, dd = 0.f;
    int i = 0;
    for (; i + 8 <= dg; i += 8) {
        int b = beg + i;
        int s[8];
#pragma unroll
        for (int k = 0; k < 8; k++) s[k] = src_csr[b + k];
        unsigned int u[8];
#pragma unroll
        for (int k = 0; k < 8; k++) u[k] = hbu[(size_t)s[k] * 64 + lane];
        float ev[8];
#pragma unroll
        for (int k = 0; k < 8; k++) ev[k] = el[(size_t)s[k] * 4 + head];
#pragma unroll
        for (int k = 0; k < 8; k++) {
            float tt = ev[k] + er_own;
            tt = fmaxf(tt, NEG_SLOPE * tt);
            float w = __expf(tt);
            float x = uas(u[k] << 16), y = uas(u[k] & 0xFFFF0000u);
            S1x += x; S1y += y;
            S2x += w * x; S2y += w * y;
            dd  += w;
        }
    }
    for (; i + 4 <= dg; i += 4) {
        int b = beg + i;
        int s[4];
#pragma unroll
        for (int k = 0; k < 4; k++) s[k] = src_csr[b + k];
        unsigned int u[4];
#pragma unroll
        for (int k = 0; k < 4; k++) u[k] = hbu[(size_t)s[k] * 64 + lane];
        float ev[4];
#pragma unroll
        for (int k = 0; k < 4; k++) ev[k] = el[(size_t)s[k] * 4 + head];
#pragma unroll
        for (int k = 0; k < 4; k++) {
            float tt = ev[k] + er_own;
            tt = fmaxf(tt, NEG_SLOPE * tt);
            float w = __expf(tt);
            float x = uas(u[k] << 16), y = uas(u[k] & 0xFFFF0000u);
            S1x += x; S1y += y;
            S2x += w * x; S2y += w * y;
            dd  += w;
        }
    }
    for (; i < dg; i++) {
        int s0 = src_csr[beg + i];
        unsigned int u0 = hbu[(size_t)s0 * 64 + lane];
        float tt = el[(size_t)s0 * 4 + head] + er_own;
        tt = fmaxf(tt, NEG_SLOPE * tt);
        float w0 = __expf(tt);
        float x0 = uas(u0 << 16), y0 = uas(u0 & 0xFFFF0000u);
        S1x += x0; S1y += y0;
        S2x += w0 * x0; S2y += w0 * y0;
        dd  += w0;
    }

    float hvx = uas(uh << 16), hvy = uas(uh & 0xFFFF0000u);
    float inv = dd > 0.f ? 1.f / dd : 0.f;
    float ox = bv.x + hvx * S1x + S2x * inv;
    float oy = bv.y + hvy * S1y + S2y * inv;
    float2 o = {ox, oy};
    ((float2*)(out + (size_t)wid * 128))[lane] = o;
}

extern "C" void kernel_launch(void* const* d_in, const int* in_sizes, int n_in,
                              void* d_out, int out_size, void* d_ws, size_t ws_size,
                              hipStream_t stream) {
    const float* feat = (const float*)d_in[0];
    const float* W_fc = (const float*)d_in[1];
    const float* al   = (const float*)d_in[2];
    const float* ar   = (const float*)d_in[3];
    const float* bias = (const float*)d_in[4];
    const int*   src  = (const int*)d_in[5];
    const int*   dst  = (const int*)d_in[6];
    const int N = in_sizes[0] / 256;
    const int E = in_sizes[5];
    const int NB = (N + 255) >> NPB_SHIFT;   // <= 512 for N <= 131072

    char* ws = (char*)d_ws;
    size_t off = 0;
    unsigned int* hbu = (unsigned int*)(ws + off); off += (size_t)N * 64 * 4; // 25.6 MB
    float* el         = (float*)(ws + off); off += (size_t)N * 4 * 4;         // 1.6 MB
    float* er         = (float*)(ws + off); off += (size_t)N * 4 * 4;         // 1.6 MB
    int* startA       = (int*)(ws + off);   off += (size_t)(N + 1) * 4;
    int* src_csr      = (int*)(ws + off);   off += (size_t)E * 4;             // 4 MB
    unsigned int* binned = (unsigned int*)(ws + off); off += (size_t)E * 4;   // 4 MB
    short* wfrag      = (short*)(ws + off); off += (size_t)72 * 64 * 8 * 2;   // 72 KB
    int* bcount       = (int*)(ws + off);   off += 2048;
    int* bbase        = (int*)(ws + off);   off += 2064;                      // NB+1
    int* bcur         = (int*)(ws + off);   off += 2048;
    int* tilectr      = (int*)(ws + off);   off += 256;

    float* out = (float*)d_out;

    int ntiles = (N + 127) / 128;
    int binWG  = (E + BIN_EDGES - 1) / BIN_EDGES;
    int gemmWG = GEMM_BLOCKS > binWG ? GEMM_BLOCKS : binWG;  // cover hist slices

    k_prep<<<18, 256, 0, stream>>>(W_fc, al, ar, wfrag, bcount, NB, tilectr);
    k_gemm<<<gemmWG, 512, 0, stream>>>(feat, wfrag, (unsigned short*)hbu,
                                       el, er, N, ntiles, tilectr, dst, bcount,
                                       E, NB);
    k_bscan<<<1, 512, 0, stream>>>(bcount, bbase, bcur, startA, NB, N);
    k_binscatter<<<binWG, 512, 0, stream>>>(src, dst, bcur, binned, E, NB);
    k_csr<<<NB, 512, 0, stream>>>(binned, bbase, startA, src_csr, N);
    k_agg<<<(N + 3) / 4, 256, 0, stream>>>(hbu, el, er, src_csr, startA,
                                           bias, out, N);
}

// Round 10
// 261.368 us; speedup vs baseline: 1.1208x; 1.0409x over previous
//
#include <hip/hip_runtime.h>
#include <hip/hip_bf16.h>
#include <hip/hip_fp16.h>
#include <math.h>

#define NEG_SLOPE 0.2f

typedef __attribute__((ext_vector_type(8))) short short8v;
typedef __attribute__((ext_vector_type(4))) float f32x4;

__device__ __forceinline__ float uas(unsigned int u) { return __uint_as_float(u); }

__device__ __forceinline__ unsigned short f2bf(float x) {
    __hip_bfloat16 b = __float2bfloat16(x);
    return *(unsigned short*)&b;
}

#define NPB_SHIFT 8
#define BCAP_SHIFT 13             // 8192 slots per bucket (mean 2558, +110 sigma)
#define BCAP (1 << BCAP_SHIFT)
#define BIN_EDGES 2048            // edges per scatter slice
#define BS_EPT    4               // 2048 / 512 threads (binscatter)
#define GEMM_BLOCKS 512           // persistent blocks (2 per CU)

// ---------------- W prep: extended bf16 fragment image -----------------------
// Extended B matrix W'[144,256]: rows 0..127 = W; rows 128..135 = head-masked
// attn projections vl[4],vr[4]; rows 136..143 = 0.  Also initializes the
// static bucket cursors (bcur[b] = b*BCAP) and the gemm tile counter --
// static capacities make bucket bases compile-time, deleting the global
// histogram + scan (k_bscan) from the critical path entirely.
__global__ void k_prep(const float* __restrict__ W, const float* __restrict__ al,
                       const float* __restrict__ ar, short* __restrict__ wfrag,
                       int* __restrict__ bcur, int NB, int* __restrict__ tilectr) {
    int p = blockIdx.x * 256 + threadIdx.x;   // n*32+kg, 0..4607
    if (p < NB) bcur[p] = p << BCAP_SHIFT;
    if (p == 0) *tilectr = 0;
    if (p >= 144 * 32) return;
    int n = p >> 5, kg = p & 31;
    float v[8];
    if (n < 128) {
        const float* wp = W + (size_t)n * 256 + kg * 8;
        float4 v0 = *(const float4*)wp;
        float4 v1 = *(const float4*)(wp + 4);
        v[0] = v0.x; v[1] = v0.y; v[2] = v0.z; v[3] = v0.w;
        v[4] = v1.x; v[5] = v1.y; v[6] = v1.z; v[7] = v1.w;
    } else if (n < 136) {
        int i = n - 128, hh = i & 3, lr = i >> 2;
        const float* av = lr ? ar : al;
#pragma unroll
        for (int j = 0; j < 8; j++) v[j] = 0.f;
        for (int c = 0; c < 32; c++) {
            float a = av[hh * 32 + c];
            const float* wp = W + (size_t)(hh * 32 + c) * 256 + kg * 8;
#pragma unroll
            for (int j = 0; j < 8; j++) v[j] += a * wp[j];
        }
    } else {
#pragma unroll
        for (int j = 0; j < 8; j++) v[j] = 0.f;
    }
    short s8[8];
#pragma unroll
    for (int j = 0; j < 8; j++) s8[j] = (short)f2bf(v[j]);
    int kstep = kg >> 2, ntile = n >> 4;
    int L     = (kg & 3) * 16 + (n & 15);
    int slot  = kstep * 9 + ntile;
    *(short8v*)&wfrag[(slot * 64 + L) * 8] = *(short8v*)s8;
}

// ---------------- MFMA GEMM + fused el/er ------------------------------------
// Persistent 512-thread blocks (8 waves, 128-row tiles), B-image staged once
// (72 KB LDS, 2 blocks/CU = 16 waves/CU); launch_bounds(512,4) -> VGPR cap
// 128 so the 16-deep A-load batch can stay in registers.  Tiles claimed from
// a global atomic counter.  Histogram tail REMOVED (static bucket bases).
__global__ __launch_bounds__(512, 4) void k_gemm(const float* __restrict__ feat,
                                                 const short* __restrict__ wfrag,
                                                 unsigned short* __restrict__ hb,
                                                 float* __restrict__ el,
                                                 float* __restrict__ er, int N,
                                                 int ntiles,
                                                 int* __restrict__ tilectr) {
    __shared__ short wlds[36864];   // 72 KB: all 72 slots, linear
    __shared__ int tsh;             // broadcast tile index
    const int t    = threadIdx.x;
    const int lane = t & 63;
    const int wave = t >> 6;        // 0..7
    const int g    = lane >> 4;     // k-quad
    const int c    = lane & 15;

    // ---- stage ALL W' slots once (4608 chunks of 16 B, linear 1:1)
#pragma unroll
    for (int i = 0; i < 9; i++) {
        int p = t + i * 512;                    // chunk 0..4607
        *(short8v*)&wlds[(size_t)p * 8] = *(const short8v*)&wfrag[(size_t)p * 8];
    }
    __syncthreads();

    // ---- dynamic tile loop (128 rows per tile, 16 per wave)
    for (;;) {
        if (t == 0) tsh = atomicAdd(tilectr, 1);
        __syncthreads();
        const int tile = tsh;
        __syncthreads();            // all read tsh before next overwrite
        if (tile >= ntiles) break;

        const int n0  = tile * 128;
        const int row = n0 + wave * 16 + c;
        const int rc  = row < N ? row : N - 1;
        const float* ap = feat + (size_t)rc * 256 + g * 8;

        float4 a4[16];
#pragma unroll
        for (int ks = 0; ks < 8; ks++) {
            a4[2 * ks]     = *(const float4*)(ap + ks * 32);
            a4[2 * ks + 1] = *(const float4*)(ap + ks * 32 + 4);
        }

        f32x4 acc[9];
#pragma unroll
        for (int nt = 0; nt < 9; nt++) acc[nt] = (f32x4){0.f, 0.f, 0.f, 0.f};

#pragma unroll
        for (int ks = 0; ks < 8; ks++) {
            float4 v0 = a4[2 * ks], v1 = a4[2 * ks + 1];
            short s8[8];
            s8[0] = (short)f2bf(v0.x); s8[1] = (short)f2bf(v0.y);
            s8[2] = (short)f2bf(v0.z); s8[3] = (short)f2bf(v0.w);
            s8[4] = (short)f2bf(v1.x); s8[5] = (short)f2bf(v1.y);
            s8[6] = (short)f2bf(v1.z); s8[7] = (short)f2bf(v1.w);
            short8v afrag = *(short8v*)s8;
#pragma unroll
            for (int nt = 0; nt < 9; nt++) {
                short8v b = *(short8v*)&wlds[(((size_t)ks * 9 + nt) * 64 + lane) * 8];
                acc[nt] = __builtin_amdgcn_mfma_f32_16x16x32_bf16(afrag, b, acc[nt], 0, 0, 0);
            }
        }

        // ---- epilogue: C/D layout col = nt*16 + c, row = wave*16 + g*4 + r
#pragma unroll
        for (int r = 0; r < 4; r++) {
            int m = n0 + wave * 16 + g * 4 + r;
            if (m < N) {
#pragma unroll
                for (int nt = 0; nt < 8; nt++)
                    hb[(size_t)m * 128 + nt * 16 + c] = f2bf(acc[nt][r]);
                float av = acc[8][r];
                if (c < 4)      el[(size_t)m * 4 + c]       = av;
                else if (c < 8) er[(size_t)m * 4 + (c - 4)] = av;
            }
        }
    }
}

// scatter edges into bucket-contiguous order, packed src|ldst<<24 (4 B/edge).
// Bucket bases are STATIC (b*BCAP); ranges claimed by atomicAdd on bcur.
// LDS-reorder so global writes are coalesced runs.
__global__ __launch_bounds__(512) void k_binscatter(const int* __restrict__ src,
                                                    const int* __restrict__ dst,
                                                    int* __restrict__ bcur,
                                                    unsigned int* __restrict__ binned,
                                                    int E, int NB) {
    __shared__ int hist[512];
    __shared__ int scn[512];
    __shared__ int lcur[512];
    __shared__ int gdelta[512];
    __shared__ int ebuf[BIN_EDGES];   // 8 KB: src per local slot
    __shared__ int dbuf[BIN_EDGES];   // 8 KB: dst per local slot
    int t = threadIdx.x;
    hist[t] = 0;
    __syncthreads();
    int wbase = blockIdx.x * BIN_EDGES;
    int base  = wbase + t;
    int ne    = E - wbase; if (ne > BIN_EDGES) ne = BIN_EDGES;
    int sv[BS_EPT], dv[BS_EPT];
#pragma unroll
    for (int k = 0; k < BS_EPT; k++) {
        int idx = base + k * 512;
        if (idx < E) {
            sv[k] = src[idx];
            dv[k] = dst[idx];
            atomicAdd(&hist[dv[k] >> NPB_SHIFT], 1);
        } else {
            dv[k] = -1;
        }
    }
    __syncthreads();
    // inclusive scan of 512 counts with 512 threads (Hillis-Steele)
    scn[t] = hist[t];
    __syncthreads();
    for (int off = 1; off < 512; off <<= 1) {
        int v = (t >= off) ? scn[t - off] : 0;
        __syncthreads();
        scn[t] += v;
        __syncthreads();
    }
    // claim global ranges; set local cursors
    if (t < NB) {
        int h  = hist[t];
        int lb = scn[t] - h;
        int g  = h ? atomicAdd(&bcur[t], h) : 0;
        gdelta[t] = g - lb;
        lcur[t]   = lb;
    }
    __syncthreads();
    // local scatter into bucket-sorted LDS order
#pragma unroll
    for (int k = 0; k < BS_EPT; k++) {
        if (dv[k] >= 0) {
            int bkt  = dv[k] >> NPB_SHIFT;
            int slot = atomicAdd(&lcur[bkt], 1);
            ebuf[slot] = sv[k];
            dbuf[slot] = dv[k];
        }
    }
    __syncthreads();
    // linear write-out: address = slot + gdelta[bucket]  (coalesced runs)
    for (int j = t; j < ne; j += 512) {
        int d = dbuf[j];
        binned[j + gdelta[d >> NPB_SHIFT]] =
            (unsigned int)ebuf[j] | ((unsigned int)(d & 255) << 24);
    }
}

// one WG per bucket: count from the final cursor, degree hist -> start/deg,
// then LDS-stage the node-sorted edges and write the bucket's CSR segment
// with one linear coalesced pass.  All coordinates are in the sparse
// (b*BCAP)-based space.
__global__ __launch_bounds__(512) void k_csr(const unsigned int* __restrict__ binned,
                                             const int* __restrict__ bcur,
                                             int* __restrict__ startA,
                                             int* __restrict__ deg,
                                             int* __restrict__ src_csr, int N) {
    __shared__ int hist[256];
    __shared__ int scn[256];
    __shared__ int cur[256];
    __shared__ int sbuf[4096];   // 16 KB staging (mean bucket 2558, +30 sigma)
    int b = blockIdx.x;
    int t = threadIdx.x;
    int base = b << BCAP_SHIFT;
    int cnt  = bcur[b] - base;
    int node0 = b << NPB_SHIFT;
    if (t < 256) hist[t] = 0;
    __syncthreads();
    for (int i = t; i < cnt; i += 512) {
        unsigned int e = binned[base + i];
        atomicAdd(&hist[e >> 24], 1);
    }
    __syncthreads();
    int h = (t < 256) ? hist[t] : 0;
    if (t < 256) scn[t] = h;
    __syncthreads();
    for (int off = 1; off < 256; off <<= 1) {
        int v = (t < 256 && t >= off) ? scn[t - off] : 0;
        __syncthreads();
        if (t < 256) scn[t] += v;
        __syncthreads();
    }
    if (t < 256) {
        int excl  = scn[t] - h;
        int gnode = node0 + t;
        if (gnode < N) { startA[gnode] = base + excl; deg[gnode] = h; }
        cur[t] = excl;
    }
    __syncthreads();
    if (cnt <= 4096) {
        for (int i = t; i < cnt; i += 512) {
            unsigned int e = binned[base + i];
            int p = atomicAdd(&cur[e >> 24], 1);
            sbuf[p] = (int)(e & 0xFFFFFFu);
        }
        __syncthreads();
        for (int i = t; i < cnt; i += 512)
            src_csr[base + i] = sbuf[i];
    } else {
        // fallback: direct scatter (degenerate distributions only)
        for (int i = t; i < cnt; i += 512) {
            unsigned int e = binned[base + i];
            int p = atomicAdd(&cur[e >> 24], 1);
            src_csr[base + p] = (int)(e & 0xFFFFFFu);
        }
    }
}

// ---------------- gather-side aggregation: one wave per dst node -------------
// unroll-8 with batched index/gather issue (8 outstanding 256-B gathers per
// wave) to hide LLC-hit latency; degree from deg[] (sparse CSR layout).
__global__ __launch_bounds__(256) void k_agg(
        const unsigned int* __restrict__ hbu,
        const float* __restrict__ el, const float* __restrict__ er,
        const int* __restrict__ src_csr, const int* __restrict__ start,
        const int* __restrict__ deg,
        const float* __restrict__ bias, float* __restrict__ out, int N) {
    int wid  = blockIdx.x * 4 + (threadIdx.x >> 6);
    int lane = threadIdx.x & 63;
    if (wid >= N) return;
    int beg = __builtin_amdgcn_readfirstlane(start[wid]);
    int dg  = __builtin_amdgcn_readfirstlane(deg[wid]);
    int head = lane >> 4;   // elements (2*lane, 2*lane+1) share one head

    float er_own = er[(size_t)wid * 4 + head];   // wave-uniform per 16-lane group
    unsigned int uh = hbu[(size_t)wid * 64 + lane];  // own row, issued early
    float2 bv = ((const float2*)bias)[lane];

    float S1x = 0.f, S1y = 0.f, S2x = 0.f, S2y = 0.f, dd = 0.f;
    int i = 0;
    for (; i + 8 <= dg; i += 8) {
        int b = beg + i;
        int s[8];
#pragma unroll
        for (int k = 0; k < 8; k++) s[k] = src_csr[b + k];
        unsigned int u[8];
#pragma unroll
        for (int k = 0; k < 8; k++) u[k] = hbu[(size_t)s[k] * 64 + lane];
        float ev[8];
#pragma unroll
        for (int k = 0; k < 8; k++) ev[k] = el[(size_t)s[k] * 4 + head];
#pragma unroll
        for (int k = 0; k < 8; k++) {
            float tt = ev[k] + er_own;
            tt = fmaxf(tt, NEG_SLOPE * tt);
            float w = __expf(tt);
            float x = uas(u[k] << 16), y = uas(u[k] & 0xFFFF0000u);
            S1x += x; S1y += y;
            S2x += w * x; S2y += w * y;
            dd  += w;
        }
    }
    for (; i + 4 <= dg; i += 4) {
        int b = beg + i;
        int s[4];
#pragma unroll
        for (int k = 0; k < 4; k++) s[k] = src_csr[b + k];
        unsigned int u[4];
#pragma unroll
        for (int k = 0; k < 4; k++) u[k] = hbu[(size_t)s[k] * 64 + lane];
        float ev[4];
#pragma unroll
        for (int k = 0; k < 4; k++) ev[k] = el[(size_t)s[k] * 4 + head];
#pragma unroll
        for (int k = 0; k < 4; k++) {
            float tt = ev[k] + er_own;
            tt = fmaxf(tt, NEG_SLOPE * tt);
            float w = __expf(tt);
            float x = uas(u[k] << 16), y = uas(u[k] & 0xFFFF0000u);
            S1x += x; S1y += y;
            S2x += w * x; S2y += w * y;
            dd  += w;
        }
    }
    for (; i < dg; i++) {
        int s0 = src_csr[beg + i];
        unsigned int u0 = hbu[(size_t)s0 * 64 + lane];
        float tt = el[(size_t)s0 * 4 + head] + er_own;
        tt = fmaxf(tt, NEG_SLOPE * tt);
        float w0 = __expf(tt);
        float x0 = uas(u0 << 16), y0 = uas(u0 & 0xFFFF0000u);
        S1x += x0; S1y += y0;
        S2x += w0 * x0; S2y += w0 * y0;
        dd  += w0;
    }

    float hvx = uas(uh << 16), hvy = uas(uh & 0xFFFF0000u);
    float inv = dd > 0.f ? 1.f / dd : 0.f;
    float ox = bv.x + hvx * S1x + S2x * inv;
    float oy = bv.y + hvy * S1y + S2y * inv;
    float2 o = {ox, oy};
    ((float2*)(out + (size_t)wid * 128))[lane] = o;
}

extern "C" void kernel_launch(void* const* d_in, const int* in_sizes, int n_in,
                              void* d_out, int out_size, void* d_ws, size_t ws_size,
                              hipStream_t stream) {
    const float* feat = (const float*)d_in[0];
    const float* W_fc = (const float*)d_in[1];
    const float* al   = (const float*)d_in[2];
    const float* ar   = (const float*)d_in[3];
    const float* bias = (const float*)d_in[4];
    const int*   src  = (const int*)d_in[5];
    const int*   dst  = (const int*)d_in[6];
    const int N = in_sizes[0] / 256;
    const int E = in_sizes[5];
    const int NB = (N + 255) >> NPB_SHIFT;   // <= 512 for N <= 131072

    char* ws = (char*)d_ws;
    size_t off = 0;
    unsigned int* hbu = (unsigned int*)(ws + off); off += (size_t)N * 64 * 4; // 25.6 MB
    float* el         = (float*)(ws + off); off += (size_t)N * 4 * 4;         // 1.6 MB
    float* er         = (float*)(ws + off); off += (size_t)N * 4 * 4;         // 1.6 MB
    int* startA       = (int*)(ws + off);   off += (size_t)N * 4;
    int* deg          = (int*)(ws + off);   off += (size_t)N * 4;
    int* src_csr      = (int*)(ws + off);   off += (size_t)NB * BCAP * 4;     // 12.8 MB
    unsigned int* binned = (unsigned int*)(ws + off); off += (size_t)NB * BCAP * 4; // 12.8 MB
    short* wfrag      = (short*)(ws + off); off += (size_t)72 * 64 * 8 * 2;   // 72 KB
    int* bcur         = (int*)(ws + off);   off += 2048;
    int* tilectr      = (int*)(ws + off);   off += 256;

    float* out = (float*)d_out;

    int ntiles = (N + 127) / 128;
    int binWG  = (E + BIN_EDGES - 1) / BIN_EDGES;

    k_prep<<<18, 256, 0, stream>>>(W_fc, al, ar, wfrag, bcur, NB, tilectr);
    k_gemm<<<GEMM_BLOCKS, 512, 0, stream>>>(feat, wfrag, (unsigned short*)hbu,
                                            el, er, N, ntiles, tilectr);
    k_binscatter<<<binWG, 512, 0, stream>>>(src, dst, bcur, binned, E, NB);
    k_csr<<<NB, 512, 0, stream>>>(binned, bcur, startA, deg, src_csr, N);
    k_agg<<<(N + 3) / 4, 256, 0, stream>>>(hbu, el, er, src_csr, startA, deg,
                                           bias, out, N);
}